// Round 1
// baseline (665.577 us; speedup 1.0000x reference)
//
#include <hip/hip_runtime.h>

#define NA 50000
#define NP 10000
#define NE 400000
#define IND 512
#define FD 128
#define HD 256

typedef unsigned int u32;

__device__ __forceinline__ u32 fkey(float f){
  u32 u = __float_as_uint(f);
  return (u & 0x80000000u) ? ~u : (u | 0x80000000u);
}
__device__ __forceinline__ float fdec(u32 k){
  return (k & 0x80000000u) ? __uint_as_float(k ^ 0x80000000u) : __uint_as_float(~k);
}

// K0: w_feat_proj[h][f] = sum_d W_feat[(h*32+d)*128 + f] * W_attn[64+d]
__global__ __launch_bounds__(256) void k_wfeat(const float* __restrict__ W_feat,
                                               const float* __restrict__ W_attn,
                                               float* __restrict__ wfp){
  __shared__ float af[32];
  int tid = threadIdx.x;
  if (tid < 32) af[tid] = W_attn[64 + tid];
  __syncthreads();
  for (int idx = tid; idx < 1024; idx += 256){
    int hh = idx >> 7, k = idx & 127;
    float s = 0.f;
    #pragma unroll
    for (int d = 0; d < 32; d++)
      s = fmaf(W_feat[(size_t)(hh*32 + d)*FD + k], af[d], s);
    wfp[idx] = s;
  }
}

// K1: z = h @ W_fc.T  (fp32 tiled, 64 rows x 256 cols per block), plus
//     s_src[n][h] = sum_d z[n][h*32+d] * W_attn[d] in the epilogue.
__global__ __launch_bounds__(256) void k_gemm_z(const float* __restrict__ h,
                                                const float* __restrict__ wfc,
                                                const float* __restrict__ wattn,
                                                float* __restrict__ z,
                                                float* __restrict__ s_src){
  __shared__ float As[32][68];    // [k][row]
  __shared__ float Bs[32][260];   // [k][col]
  int tid = threadIdx.x;
  int row0 = blockIdx.x * 64;
  int tx = tid & 15, ty = tid >> 4;     // rows tx*4.., cols ty*16..
  float acc[4][16];
  #pragma unroll
  for (int i = 0; i < 4; i++)
    #pragma unroll
    for (int j = 0; j < 16; j++) acc[i][j] = 0.f;

  int kc = tid >> 5;   // 0..7
  int rr = tid & 31;   // 0..31

  for (int k0 = 0; k0 < IND; k0 += 32){
    #pragma unroll
    for (int half = 0; half < 2; half++){
      int r = half*32 + rr;
      int grow = row0 + r;
      float4 v = make_float4(0.f,0.f,0.f,0.f);
      if (grow < NA) v = *(const float4*)(h + (size_t)grow*IND + k0 + kc*4);
      As[kc*4+0][r] = v.x; As[kc*4+1][r] = v.y; As[kc*4+2][r] = v.z; As[kc*4+3][r] = v.w;
    }
    #pragma unroll
    for (int kc2 = 0; kc2 < 8; kc2++){
      float4 w = *(const float4*)(wfc + (size_t)tid*IND + k0 + kc2*4);
      Bs[kc2*4+0][tid] = w.x; Bs[kc2*4+1][tid] = w.y; Bs[kc2*4+2][tid] = w.z; Bs[kc2*4+3][tid] = w.w;
    }
    __syncthreads();
    #pragma unroll
    for (int kk = 0; kk < 32; kk++){
      float4 av = *(const float4*)&As[kk][tx*4];
      float a[4] = {av.x, av.y, av.z, av.w};
      float b[16];
      #pragma unroll
      for (int jj = 0; jj < 4; jj++){
        float4 bv = *(const float4*)&Bs[kk][ty*16 + jj*4];
        b[jj*4+0] = bv.x; b[jj*4+1] = bv.y; b[jj*4+2] = bv.z; b[jj*4+3] = bv.w;
      }
      #pragma unroll
      for (int i = 0; i < 4; i++)
        #pragma unroll
        for (int j = 0; j < 16; j++)
          acc[i][j] = fmaf(a[i], b[j], acc[i][j]);
    }
    __syncthreads();
  }
  // store z
  #pragma unroll
  for (int i = 0; i < 4; i++){
    int grow = row0 + tx*4 + i;
    if (grow < NA){
      #pragma unroll
      for (int jj = 0; jj < 4; jj++){
        float4 v = make_float4(acc[i][jj*4+0], acc[i][jj*4+1], acc[i][jj*4+2], acc[i][jj*4+3]);
        *(float4*)(z + (size_t)grow*HD + ty*16 + jj*4) = v;
      }
    }
  }
  // s_src epilogue: partial over this thread's 16 cols, combine pairs via LDS
  float aS[16];
  #pragma unroll
  for (int j = 0; j < 16; j++) aS[j] = wattn[(ty & 1)*16 + j];
  float part[4];
  #pragma unroll
  for (int i = 0; i < 4; i++){
    float s = 0.f;
    #pragma unroll
    for (int j = 0; j < 16; j++) s = fmaf(acc[i][j], aS[j], s);
    part[i] = s;
  }
  __syncthreads();              // all Bs reads done (loop-end sync), safe to reuse
  float (*sred)[17] = reinterpret_cast<float(*)[17]>(&Bs[0][0]);  // [64][17]
  #pragma unroll
  for (int i = 0; i < 4; i++) sred[tx*4 + i][ty] = part[i];
  __syncthreads();
  #pragma unroll
  for (int it = 0; it < 2; it++){
    int idx = it*256 + tid;          // 0..511 = 64 rows x 8 heads
    int r = idx >> 3, hh = idx & 7;
    int grow = row0 + r;
    if (grow < NA)
      s_src[(size_t)grow*8 + hh] = sred[r][2*hh] + sred[r][2*hh + 1];
  }
}

// K2: per-edge: s_feat = srl_emb[e]·wfp[h], e_val = leaky_relu(s_src[src]+s_feat),
//     atomicMax segment max, histogram counts[dst].
__global__ __launch_bounds__(256) void k_edge(const float* __restrict__ srl,
                                              const int* __restrict__ src,
                                              const int* __restrict__ dst,
                                              const float* __restrict__ s_src,
                                              const float* __restrict__ wfp,
                                              float* __restrict__ e_vals,
                                              u32* __restrict__ segmax,
                                              u32* __restrict__ counts){
  __shared__ float S[64][132];
  __shared__ float Wp[8][132];
  __shared__ int sSrc[64], sDst[64];
  int tid = threadIdx.x;
  int e0 = blockIdx.x * 64;
  {
    float4 v = ((const float4*)wfp)[tid];       // 256 float4 = 1024 floats
    int hh = tid >> 5, k = (tid & 31) * 4;
    *(float4*)&Wp[hh][k] = v;
  }
  if (tid < 64){ sSrc[tid] = src[e0 + tid]; sDst[tid] = dst[e0 + tid]; }
  #pragma unroll
  for (int m = 0; m < 8; m++){
    int idx = m*256 + tid;
    int r = idx >> 5, c = (idx & 31) * 4;
    float4 v = *(const float4*)(srl + (size_t)(e0 + r)*FD + c);
    *(float4*)&S[r][c] = v;
  }
  __syncthreads();
  #pragma unroll
  for (int m = 0; m < 2; m++){
    int item = m*256 + tid;
    int el = item >> 3, hh = item & 7;
    float s = 0.f;
    #pragma unroll 8
    for (int k4 = 0; k4 < 32; k4++){
      float4 a = *(const float4*)&S[el][k4*4];
      float4 b = *(const float4*)&Wp[hh][k4*4];
      s += a.x*b.x + a.y*b.y + a.z*b.z + a.w*b.w;
    }
    float x = s + s_src[(size_t)sSrc[el]*8 + hh];
    float ev = x > 0.f ? x : 0.01f * x;
    e_vals[(size_t)e0*8 + item] = ev;
    atomicMax(&segmax[(size_t)sDst[el]*8 + hh], fkey(ev));
  }
  if (tid < 64) atomicAdd(&counts[sDst[tid]], 1u);
}

// K3: exclusive scan of counts[NP] -> row_start, cursor (single block)
__global__ __launch_bounds__(1024) void k_scan(const u32* __restrict__ counts,
                                               u32* __restrict__ row_start,
                                               u32* __restrict__ cursor){
  __shared__ u32 sh[1024];
  int tid = threadIdx.x;
  u32 carry = 0;
  for (int base = 0; base < NP; base += 1024){
    int i = base + tid;
    u32 c = (i < NP) ? counts[i] : 0u;
    sh[tid] = c;
    __syncthreads();
    for (int off = 1; off < 1024; off <<= 1){
      u32 t = (tid >= off) ? sh[tid - off] : 0u;
      __syncthreads();
      sh[tid] += t;
      __syncthreads();
    }
    u32 excl = carry + sh[tid] - c;
    if (i < NP){ row_start[i] = excl; cursor[i] = excl; }
    carry += sh[1023];
    __syncthreads();
  }
}

// K4: scatter edge ids into CSR order
__global__ __launch_bounds__(256) void k_scatter(const int* __restrict__ dst,
                                                 u32* __restrict__ cursor,
                                                 u32* __restrict__ sorted){
  int t = blockIdx.x * 256 + threadIdx.x;
  if (t < NE){
    u32 pos = atomicAdd(&cursor[dst[t]], 1u);
    sorted[pos] = (u32)t;
  }
}

// K5: one block per destination segment: out = (sum ex * z[src]) / denom
__global__ __launch_bounds__(256) void k_agg(const float* __restrict__ z,
                                             const int* __restrict__ src,
                                             const float* __restrict__ e_vals,
                                             const u32* __restrict__ segmax,
                                             const u32* __restrict__ row_start,
                                             const u32* __restrict__ counts,
                                             const u32* __restrict__ sorted,
                                             float* __restrict__ out){
  int p = blockIdx.x;
  int tid = threadIdx.x;
  int head = tid >> 5;
  __shared__ int sId[64], sSrc[64];
  __shared__ float sEv[64][9];
  __shared__ float sDen[8];
  int n = (int)counts[p];
  int start = (int)row_start[p];
  float m = fdec(segmax[(size_t)p*8 + head]);
  float acc = 0.f, dsum = 0.f;
  for (int base = 0; base < n; base += 64){
    int take = min(64, n - base);
    __syncthreads();
    if (tid < take){
      int id = (int)sorted[start + base + tid];
      sId[tid] = id;
      sSrc[tid] = src[id];
    }
    __syncthreads();
    for (int idx = tid; idx < take*8; idx += 256){
      int el = idx >> 3, hh = idx & 7;
      sEv[el][hh] = e_vals[(size_t)sId[el]*8 + hh];
    }
    __syncthreads();
    for (int j = 0; j < take; j++){
      float ex = __expf(sEv[j][head] - m);
      acc = fmaf(ex, z[(size_t)sSrc[j]*HD + tid], acc);
      dsum += ex;
    }
  }
  if ((tid & 31) == 0) sDen[head] = dsum;
  __syncthreads();
  out[(size_t)p*HD + tid] = (n > 0) ? acc / sDen[head] : 0.f;
}

extern "C" void kernel_launch(void* const* d_in, const int* in_sizes, int n_in,
                              void* d_out, int out_size, void* d_ws, size_t ws_size,
                              hipStream_t stream){
  (void)in_sizes; (void)n_in; (void)out_size; (void)ws_size;
  const float* h    = (const float*)d_in[0];
  const float* srl  = (const float*)d_in[1];
  const int*   src  = (const int*)d_in[2];
  const int*   dst  = (const int*)d_in[3];
  const float* wfc  = (const float*)d_in[4];
  const float* wfeat= (const float*)d_in[5];
  const float* wattn= (const float*)d_in[6];
  float* out = (float*)d_out;

  char* ws = (char*)d_ws;
  float* z        = (float*)(ws + 0);          // 51,200,000 B
  float* s_src    = (float*)(ws + 51200000);   //  1,600,000 B
  float* e_vals   = (float*)(ws + 52800000);   // 12,800,000 B
  u32*   segmax   = (u32*)  (ws + 65600000);   //    320,000 B [zeroed]
  u32*   counts   = (u32*)  (ws + 65920000);   //     40,000 B [zeroed]
  u32*   row_start= (u32*)  (ws + 65960000);   //     40,000 B
  u32*   cursor   = (u32*)  (ws + 66000000);   //     40,000 B
  u32*   sorted   = (u32*)  (ws + 66040000);   //  1,600,000 B
  float* wfp      = (float*)(ws + 67640000);   //      4,096 B

  hipMemsetAsync(segmax, 0, 360000, stream);   // segmax + counts (contiguous)

  k_wfeat  <<<1,    256, 0, stream>>>(wfeat, wattn, wfp);
  k_gemm_z <<<782,  256, 0, stream>>>(h, wfc, wattn, z, s_src);
  k_edge   <<<6250, 256, 0, stream>>>(srl, src, dst, s_src, wfp, e_vals, segmax, counts);
  k_scan   <<<1,   1024, 0, stream>>>(counts, row_start, cursor);
  k_scatter<<<1563, 256, 0, stream>>>(dst, cursor, sorted);
  k_agg    <<<NP,   256, 0, stream>>>(z, src, e_vals, segmax, row_start, counts, sorted, out);
}

// Round 2
// 516.036 us; speedup vs baseline: 1.2898x; 1.2898x over previous
//
#include <hip/hip_runtime.h>

#define NA 50000
#define NP 10000
#define NE 400000
#define IND 512
#define FD 128
#define HD 256

typedef unsigned int u32;
typedef __attribute__((ext_vector_type(8))) short bf16x8;
typedef __attribute__((ext_vector_type(4))) float f32x4;
typedef __attribute__((ext_vector_type(4))) unsigned short us4;

__device__ __forceinline__ u32 fkey(float f){
  u32 u = __float_as_uint(f);
  return (u & 0x80000000u) ? ~u : (u | 0x80000000u);
}
__device__ __forceinline__ float fdec(u32 k){
  return (k & 0x80000000u) ? __uint_as_float(k ^ 0x80000000u) : __uint_as_float(~k);
}
__device__ __forceinline__ unsigned short f2bf(float f){
  u32 u = __float_as_uint(f);
  u32 r = (u + 0x7FFFu + ((u >> 16) & 1u)) >> 16;   // RNE
  return (unsigned short)r;
}
__device__ __forceinline__ us4 cvt4(float4 v){
  us4 r;
  r.x = f2bf(v.x); r.y = f2bf(v.y); r.z = f2bf(v.z); r.w = f2bf(v.w);
  return r;
}

// K0: w_feat_proj[h][f] = sum_d W_feat[(h*32+d)*128 + f] * W_attn[64+d]
__global__ __launch_bounds__(256) void k_wfeat(const float* __restrict__ W_feat,
                                               const float* __restrict__ W_attn,
                                               float* __restrict__ wfp){
  __shared__ float af[32];
  int tid = threadIdx.x;
  if (tid < 32) af[tid] = W_attn[64 + tid];
  __syncthreads();
  for (int idx = tid; idx < 1024; idx += 256){
    int hh = idx >> 7, k = idx & 127;
    float s = 0.f;
    #pragma unroll
    for (int d = 0; d < 32; d++)
      s = fmaf(W_feat[(size_t)(hh*32 + d)*FD + k], af[d], s);
    wfp[idx] = s;
  }
}

// K1: z = h @ W_fc.T via bf16 MFMA (BM=64 x BN=256, BK=32, 4 waves),
//     s_src epilogue from fp32 accumulators.
#define BM 64
#define BN 256
#define BK 32
#define LDA 40   // padded row stride in bf16 elements (80B = 5*16B, keeps b128 align)

__global__ __launch_bounds__(256,3) void k_gemm_z(const float* __restrict__ h,
                                                  const float* __restrict__ wfc,
                                                  const float* __restrict__ wattn,
                                                  float* __restrict__ z,
                                                  float* __restrict__ s_src){
  __shared__ unsigned short As[2][BM*LDA];   // 2*64*40*2B  = 10240 B
  __shared__ unsigned short Bs[2][BN*LDA];   // 2*256*40*2B = 40960 B

  const int tid = threadIdx.x;
  const int lane = tid & 63, wv = tid >> 6;
  const int lr = lane & 15, lk = lane >> 4;
  const int row0 = blockIdx.x * BM;

  f32x4 acc[4][4];
  #pragma unroll
  for (int m = 0; m < 4; m++)
    #pragma unroll
    for (int n = 0; n < 4; n++) acc[m][n] = (f32x4){0.f,0.f,0.f,0.f};

  // staging index decomposition (A: 512 float4, B: 2048 float4)
  const int ar = tid >> 3, ac4 = tid & 7;          // +i*256 -> rows ar, ar+32

  float4 na[2], nb[8];

  // ---- prologue: load k0=0 ----
  #pragma unroll
  for (int i = 0; i < 2; i++){
    int r = ar + i*32;
    int gr = row0 + r;
    na[i] = (gr < NA) ? *(const float4*)(h + (size_t)gr*IND + ac4*4)
                      : make_float4(0.f,0.f,0.f,0.f);
  }
  #pragma unroll
  for (int i = 0; i < 8; i++){
    int r = ar + i*32;
    nb[i] = *(const float4*)(wfc + (size_t)r*IND + ac4*4);
  }
  #pragma unroll
  for (int i = 0; i < 2; i++)
    *(us4*)&As[0][(ar + i*32)*LDA + ac4*4] = cvt4(na[i]);
  #pragma unroll
  for (int i = 0; i < 8; i++)
    *(us4*)&Bs[0][(ar + i*32)*LDA + ac4*4] = cvt4(nb[i]);
  __syncthreads();

  for (int t = 0; t < 16; t++){
    const int cur = t & 1;
    // issue next-tile global loads (overlap with MFMA below)
    if (t < 15){
      const int k0 = (t+1)*BK;
      #pragma unroll
      for (int i = 0; i < 2; i++){
        int r = ar + i*32;
        int gr = row0 + r;
        na[i] = (gr < NA) ? *(const float4*)(h + (size_t)gr*IND + k0 + ac4*4)
                          : make_float4(0.f,0.f,0.f,0.f);
      }
      #pragma unroll
      for (int i = 0; i < 8; i++){
        int r = ar + i*32;
        nb[i] = *(const float4*)(wfc + (size_t)r*IND + k0 + ac4*4);
      }
    }
    // compute from buf[cur]
    bf16x8 af[4], bf[4];
    #pragma unroll
    for (int m = 0; m < 4; m++)
      af[m] = *(const bf16x8*)&As[cur][(m*16 + lr)*LDA + lk*8];
    #pragma unroll
    for (int n = 0; n < 4; n++)
      bf[n] = *(const bf16x8*)&Bs[cur][(wv*64 + n*16 + lr)*LDA + lk*8];
    #pragma unroll
    for (int m = 0; m < 4; m++)
      #pragma unroll
      for (int n = 0; n < 4; n++)
        acc[m][n] = __builtin_amdgcn_mfma_f32_16x16x32_bf16(af[m], bf[n], acc[m][n], 0, 0, 0);
    // write next tile into the other buffer
    if (t < 15){
      const int nxt = cur ^ 1;
      #pragma unroll
      for (int i = 0; i < 2; i++)
        *(us4*)&As[nxt][(ar + i*32)*LDA + ac4*4] = cvt4(na[i]);
      #pragma unroll
      for (int i = 0; i < 8; i++)
        *(us4*)&Bs[nxt][(ar + i*32)*LDA + ac4*4] = cvt4(nb[i]);
    }
    __syncthreads();
  }

  // ---- epilogue: store z ----
  #pragma unroll
  for (int m = 0; m < 4; m++){
    #pragma unroll
    for (int j = 0; j < 4; j++){
      int gr = row0 + m*16 + lk*4 + j;
      if (gr < NA){
        #pragma unroll
        for (int n = 0; n < 4; n++)
          z[(size_t)gr*HD + wv*64 + n*16 + lr] = acc[m][n][j];
      }
    }
  }
  // ---- s_src: rows of this block, heads 2*wv, 2*wv+1 ----
  float a0 = wattn[lr], a1 = wattn[16 + lr];
  #pragma unroll
  for (int m = 0; m < 4; m++){
    #pragma unroll
    for (int j = 0; j < 4; j++){
      #pragma unroll
      for (int hl = 0; hl < 2; hl++){
        float s = acc[m][2*hl][j] * a0 + acc[m][2*hl+1][j] * a1;
        s += __shfl_xor(s, 1);
        s += __shfl_xor(s, 2);
        s += __shfl_xor(s, 4);
        s += __shfl_xor(s, 8);
        int gr = row0 + m*16 + lk*4 + j;
        if (lr == 0 && gr < NA)
          s_src[(size_t)gr*8 + wv*2 + hl] = s;
      }
    }
  }
}

// K2: per-edge logits + segment max + histogram
__global__ __launch_bounds__(256) void k_edge(const float* __restrict__ srl,
                                              const int* __restrict__ src,
                                              const int* __restrict__ dst,
                                              const float* __restrict__ s_src,
                                              const float* __restrict__ wfp,
                                              float* __restrict__ e_vals,
                                              u32* __restrict__ segmax,
                                              u32* __restrict__ counts){
  __shared__ float S[64][132];
  __shared__ float Wp[8][132];
  __shared__ int sSrc[64], sDst[64];
  int tid = threadIdx.x;
  int e0 = blockIdx.x * 64;
  {
    float4 v = ((const float4*)wfp)[tid];
    int hh = tid >> 5, k = (tid & 31) * 4;
    *(float4*)&Wp[hh][k] = v;
  }
  if (tid < 64){ sSrc[tid] = src[e0 + tid]; sDst[tid] = dst[e0 + tid]; }
  #pragma unroll
  for (int m = 0; m < 8; m++){
    int idx = m*256 + tid;
    int r = idx >> 5, c = (idx & 31) * 4;
    float4 v = *(const float4*)(srl + (size_t)(e0 + r)*FD + c);
    *(float4*)&S[r][c] = v;
  }
  __syncthreads();
  #pragma unroll
  for (int m = 0; m < 2; m++){
    int item = m*256 + tid;
    int el = item >> 3, hh = item & 7;
    float s = 0.f;
    #pragma unroll 8
    for (int k4 = 0; k4 < 32; k4++){
      float4 a = *(const float4*)&S[el][k4*4];
      float4 b = *(const float4*)&Wp[hh][k4*4];
      s += a.x*b.x + a.y*b.y + a.z*b.z + a.w*b.w;
    }
    float x = s + s_src[(size_t)sSrc[el]*8 + hh];
    float ev = x > 0.f ? x : 0.01f * x;
    e_vals[(size_t)e0*8 + item] = ev;
    atomicMax(&segmax[(size_t)sDst[el]*8 + hh], fkey(ev));
  }
  if (tid < 64) atomicAdd(&counts[sDst[tid]], 1u);
}

// K3: exclusive scan of counts[NP] via shfl (single block, 256 threads x 40 elems)
__global__ __launch_bounds__(256) void k_scan(const u32* __restrict__ counts,
                                              u32* __restrict__ row_start,
                                              u32* __restrict__ cursor){
  __shared__ u32 wsum[4];
  int tid = threadIdx.x;
  int lane = tid & 63, wv = tid >> 6;
  const int CH = 40;
  int base = tid * CH;
  u32 loc[CH];
  u32 s = 0;
  #pragma unroll
  for (int i = 0; i < CH; i++){
    int g = base + i;
    u32 c = (g < NP) ? counts[g] : 0u;
    loc[i] = c; s += c;
  }
  u32 inc = s;
  #pragma unroll
  for (int off = 1; off < 64; off <<= 1){
    u32 v = __shfl_up(inc, off);
    if (lane >= off) inc += v;
  }
  if (lane == 63) wsum[wv] = inc;
  __syncthreads();
  u32 woff = 0;
  #pragma unroll
  for (int w = 0; w < 4; w++) if (w < wv) woff += wsum[w];
  u32 run = woff + inc - s;
  #pragma unroll
  for (int i = 0; i < CH; i++){
    int g = base + i;
    if (g < NP){ row_start[g] = run; cursor[g] = run; }
    run += loc[i];
  }
}

// K4: scatter edge ids into CSR order
__global__ __launch_bounds__(256) void k_scatter(const int* __restrict__ dst,
                                                 u32* __restrict__ cursor,
                                                 u32* __restrict__ sorted){
  int t = blockIdx.x * 256 + threadIdx.x;
  if (t < NE){
    u32 pos = atomicAdd(&cursor[dst[t]], 1u);
    sorted[pos] = (u32)t;
  }
}

// K5: one block per destination segment
__global__ __launch_bounds__(256) void k_agg(const float* __restrict__ z,
                                             const int* __restrict__ src,
                                             const float* __restrict__ e_vals,
                                             const u32* __restrict__ segmax,
                                             const u32* __restrict__ row_start,
                                             const u32* __restrict__ counts,
                                             const u32* __restrict__ sorted,
                                             float* __restrict__ out){
  int p = blockIdx.x;
  int tid = threadIdx.x;
  int head = tid >> 5;
  __shared__ int sId[64], sSrc[64];
  __shared__ float sEv[64][9];
  __shared__ float sDen[8];
  int n = (int)counts[p];
  int start = (int)row_start[p];
  float m = fdec(segmax[(size_t)p*8 + head]);
  float acc = 0.f, dsum = 0.f;
  for (int base = 0; base < n; base += 64){
    int take = min(64, n - base);
    __syncthreads();
    if (tid < take){
      int id = (int)sorted[start + base + tid];
      sId[tid] = id;
      sSrc[tid] = src[id];
    }
    __syncthreads();
    for (int idx = tid; idx < take*8; idx += 256){
      int el = idx >> 3, hh = idx & 7;
      sEv[el][hh] = e_vals[(size_t)sId[el]*8 + hh];
    }
    __syncthreads();
    for (int j = 0; j < take; j++){
      float ex = __expf(sEv[j][head] - m);
      acc = fmaf(ex, z[(size_t)sSrc[j]*HD + tid], acc);
      dsum += ex;
    }
  }
  if ((tid & 31) == 0) sDen[head] = dsum;
  __syncthreads();
  out[(size_t)p*HD + tid] = (n > 0) ? acc / sDen[head] : 0.f;
}

extern "C" void kernel_launch(void* const* d_in, const int* in_sizes, int n_in,
                              void* d_out, int out_size, void* d_ws, size_t ws_size,
                              hipStream_t stream){
  (void)in_sizes; (void)n_in; (void)out_size; (void)ws_size;
  const float* h    = (const float*)d_in[0];
  const float* srl  = (const float*)d_in[1];
  const int*   src  = (const int*)d_in[2];
  const int*   dst  = (const int*)d_in[3];
  const float* wfc  = (const float*)d_in[4];
  const float* wfeat= (const float*)d_in[5];
  const float* wattn= (const float*)d_in[6];
  float* out = (float*)d_out;

  char* ws = (char*)d_ws;
  float* z        = (float*)(ws + 0);          // 51,200,000 B
  float* s_src    = (float*)(ws + 51200000);   //  1,600,000 B
  float* e_vals   = (float*)(ws + 52800000);   // 12,800,000 B
  u32*   segmax   = (u32*)  (ws + 65600000);   //    320,000 B [zeroed]
  u32*   counts   = (u32*)  (ws + 65920000);   //     40,000 B [zeroed]
  u32*   row_start= (u32*)  (ws + 65960000);   //     40,000 B
  u32*   cursor   = (u32*)  (ws + 66000000);   //     40,000 B
  u32*   sorted   = (u32*)  (ws + 66040000);   //  1,600,000 B
  float* wfp      = (float*)(ws + 67640000);   //      4,096 B

  hipMemsetAsync(segmax, 0, 360000, stream);

  k_wfeat  <<<1,    256, 0, stream>>>(wfeat, wattn, wfp);
  k_gemm_z <<<782,  256, 0, stream>>>(h, wfc, wattn, z, s_src);
  k_edge   <<<6250, 256, 0, stream>>>(srl, src, dst, s_src, wfp, e_vals, segmax, counts);
  k_scan   <<<1,    256, 0, stream>>>(counts, row_start, cursor);
  k_scatter<<<1563, 256, 0, stream>>>(dst, cursor, sorted);
  k_agg    <<<NP,   256, 0, stream>>>(z, src, e_vals, segmax, row_start, counts, sorted, out);
}